// Round 6
// baseline (582.197 us; speedup 1.0000x reference)
//
#include <hip/hip_runtime.h>
#include <math.h>

// ---------------- problem constants (from setup_inputs) ----------------
constexpr int Bc = 2;          // batch
constexpr int Cc = 64;         // channels
constexpr int Nc = 50000;      // points
constexpr int Kc = 8;          // neighbours
constexpr int Pc = 8;          // points per wave (register blocking)
constexpr int NBATCH = (Bc * Nc) / Pc;  // 12500, exact

// packed-weight layout inside d_ws (float offsets)
constexpr int SV_OFF  = 0;      // shape_vec[4]
constexpr int PH_OFF  = 16;     // 17 groups * 64 c * 4 = 4352
constexpr int NH1_OFF = 4384;   // 4352
constexpr int DL_OFF  = 8768;   // 18 groups * 24 o * 4 = 1728
constexpr int NH2_OFF = 10496;  // 9 k * 16 cg * 64 c * 4 = 36864
constexpr int XT_OFF  = 65536;  // transposed bf16 volume starts here (float offset)
constexpr size_t XT_USHORTS = (size_t)Bc * 64 * 64 * 64 * 64;  // 33,554,432 ushorts = 64 MB

// ---------------- helpers ----------------
__device__ __forceinline__ float gelu_exact(float v) {
    return 0.5f * v * (1.0f + erff(v * 0.70710678118654752f));
}

__device__ __forceinline__ ushort f2bf(float f) {           // RNE f32 -> bf16 bits
    unsigned u = __float_as_uint(f);
    unsigned r = (u + 0x7FFFu + ((u >> 16) & 1u)) >> 16;
    return (ushort)r;
}
__device__ __forceinline__ float bf2f(ushort u) {
    return __uint_as_float(((unsigned)u) << 16);
}

// ---- fallback (channel-major f32) sampling ----
__device__ __forceinline__ float sample_cm(const float* __restrict__ xb,
                                           float gx, float gy, float gz) {
    float ix = fminf(fmaxf((gx + 1.0f) * 31.5f, 0.0f), 63.0f);
    float iy = fminf(fmaxf((gy + 1.0f) * 31.5f, 0.0f), 63.0f);
    float iz = fminf(fmaxf((gz + 1.0f) * 31.5f, 0.0f), 63.0f);
    float fx0 = floorf(ix), fy0 = floorf(iy), fz0 = floorf(iz);
    int x0 = (int)fx0, y0 = (int)fy0, z0 = (int)fz0;
    float fx = ix - fx0, fy = iy - fy0, fz = iz - fz0;
    int x1 = (x0 < 63) ? x0 + 1 : 63;
    int dy = (y0 < 63) ? 64 : 0;
    int dz = (z0 < 63) ? 4096 : 0;
    const float* r = xb + ((z0 << 12) + (y0 << 6));
    float v000 = r[x0],           v001 = r[x1];
    float v010 = r[x0 + dy],      v011 = r[x1 + dy];
    float v100 = r[x0 + dz],      v101 = r[x1 + dz];
    float v110 = r[x0 + dy + dz], v111 = r[x1 + dy + dz];
    float c00 = fmaf(fx, v001 - v000, v000);
    float c01 = fmaf(fx, v011 - v010, v010);
    float c10 = fmaf(fx, v101 - v100, v100);
    float c11 = fmaf(fx, v111 - v110, v110);
    float c0  = fmaf(fy, c01 - c00, c00);
    float c1  = fmaf(fy, c11 - c10, c10);
    return fmaf(fz, c1 - c0, c0);
}

// ---- transposed channel-minor bf16 sampling: 1 cache line per corner ----
__device__ __forceinline__ float sample_tr(const ushort* __restrict__ xtb, int lane,
                                           float gx, float gy, float gz) {
    float ix = fminf(fmaxf((gx + 1.0f) * 31.5f, 0.0f), 63.0f);
    float iy = fminf(fmaxf((gy + 1.0f) * 31.5f, 0.0f), 63.0f);
    float iz = fminf(fmaxf((gz + 1.0f) * 31.5f, 0.0f), 63.0f);
    float fx0 = floorf(ix), fy0 = floorf(iy), fz0 = floorf(iz);
    int x0 = (int)fx0, y0 = (int)fy0, z0 = (int)fz0;
    float fx = ix - fx0, fy = iy - fy0, fz = iz - fz0;
    int dx = (x0 < 63) ? 64 : 0;        // +1 in x = +64 ushorts
    int dy = (y0 < 63) ? 4096 : 0;      // +1 in y
    int dz = (z0 < 63) ? 262144 : 0;    // +1 in z
    const ushort* r = xtb + ((((z0 << 12) + (y0 << 6) + x0) << 6) + lane);
    float v000 = bf2f(r[0]),            v001 = bf2f(r[dx]);
    float v010 = bf2f(r[dy]),           v011 = bf2f(r[dy + dx]);
    float v100 = bf2f(r[dz]),           v101 = bf2f(r[dz + dx]);
    float v110 = bf2f(r[dz + dy]),      v111 = bf2f(r[dz + dy + dx]);
    float c00 = fmaf(fx, v001 - v000, v000);
    float c01 = fmaf(fx, v011 - v010, v010);
    float c10 = fmaf(fx, v101 - v100, v100);
    float c11 = fmaf(fx, v111 - v110, v110);
    float c0  = fmaf(fy, c01 - c00, c00);
    float c1  = fmaf(fy, c11 - c10, c10);
    return fmaf(fz, c1 - c0, c0);
}

// ---------------- weight packing ----------------
__global__ void sb_pack(const float* __restrict__ shape_w, const float* __restrict__ shape_b,
                        const float* __restrict__ delta_w, const float* __restrict__ ph_w,
                        const float* __restrict__ nh1_w, const float* __restrict__ nh2_w,
                        float* __restrict__ ws) {
    int tid = blockIdx.x * blockDim.x + threadIdx.x;
    int nt  = gridDim.x * blockDim.x;
    if (tid < 4) {
        float s = shape_w[tid * 4 + 0] + shape_w[tid * 4 + 1] +
                  shape_w[tid * 4 + 2] + shape_w[tid * 4 + 3];
        ws[SV_OFF + tid] = 64.0f * s + shape_b[tid];
    }
    for (int e = tid; e < 4352; e += nt) {
        int jg = e >> 8, c = (e >> 2) & 63, jl = e & 3, j = jg * 4 + jl;
        ws[PH_OFF + e]  = (j < 67) ? ph_w[c * 67 + j]  : 0.0f;
        ws[NH1_OFF + e] = (j < 67) ? nh1_w[c * 67 + j] : 0.0f;
    }
    for (int e = tid; e < 1728; e += nt) {
        int jg = e / 96, r = e - jg * 96, o = r >> 2, jl = r & 3, j = jg * 4 + jl;
        ws[DL_OFF + e] = (j < 71) ? delta_w[o * 71 + j] : 0.0f;
    }
    for (int e = tid; e < 36864; e += nt) {
        int cl = e & 3, c = (e >> 2) & 63, t = e >> 8, cg = t & 15, kk = t >> 4;
        ws[NH2_OFF + e] = nh2_w[(c * 64 + (cg * 4 + cl)) * 9 + kk];
    }
}

// ---------------- transpose x [B,C,64^3] f32 -> xt [B,64^3,C] bf16 ----------------
__global__ __launch_bounds__(256) void sb_transpose(const float* __restrict__ x,
                                                    ushort* __restrict__ xt) {
    __shared__ float tile[64][65];
    int blk = blockIdx.x;              // b*4096 + (z*64+y)
    int b = blk >> 12, zy = blk & 4095;
    const float* __restrict__ src = x + ((size_t)b << 24) + zy * 64;
    unsigned* __restrict__ dst32 = (unsigned*)(xt + ((size_t)b << 24) + (size_t)zy * 4096);
    int t = threadIdx.x;
    int xx = t & 63, c0 = t >> 6;
#pragma unroll
    for (int i = 0; i < 16; ++i) {
        int c = i * 4 + c0;
        tile[c][xx] = src[((size_t)c << 18) + xx];   // coalesced 256B per c-row
    }
    __syncthreads();
    int cp = t & 31, xs0 = t >> 5;                   // cp = channel pair, 8 xs rows/iter
#pragma unroll
    for (int i = 0; i < 8; ++i) {
        int xs = i * 8 + xs0;
        unsigned lo = f2bf(tile[cp * 2][xs]);
        unsigned hi = f2bf(tile[cp * 2 + 1][xs]);
        dst32[xs * 32 + cp] = lo | (hi << 16);       // 128B per 32-lane group
    }
}

// ---------------- main fused kernel: 1 wave = Pc points, lane = channel ----------------
template <bool TR>
__global__ __launch_bounds__(64) void sb_main(
        const float* __restrict__ x, const ushort* __restrict__ xt,
        const float* __restrict__ verts, const float* __restrict__ ws,
        const float* __restrict__ ph_b, const float* __restrict__ delta_b,
        const float* __restrict__ nh1_b, float* __restrict__ out) {
    __shared__ __align__(16) float stage[Pc][72];   // nin column broadcast buffer
    __shared__ __align__(16) float hstage[Pc][64];  // gelu(h) broadcast buffer
    __shared__ float cst[Pc][4];                    // point coords (x,y,z)
    __shared__ float dls[Pc][24];                   // delta outputs per point

    const int lane  = threadIdx.x;             // output / feature channel
    const int g0    = blockIdx.x * Pc;         // first global point id
    const int b     = g0 / Nc;                 // uniform within wave (50000 % 8 == 0)
    const float*  __restrict__ xb  = x  + ((size_t)(b * Cc + lane) << 18);  // fallback base
    const ushort* __restrict__ xtb = xt + ((size_t)b << 24);                // bf16 volume base

    const float sv0 = ws[SV_OFF + 0], sv1 = ws[SV_OFF + 1];
    const float sv2 = ws[SV_OFF + 2], sv3 = ws[SV_OFF + 3];

    // ---- point samples: full unroll for gather MLP (round-3 config) ----
#pragma unroll
    for (int p = 0; p < Pc; ++p) {
        const float* vp = verts + (size_t)(g0 + p) * 3;
        float vx = vp[0], vy = vp[1], vz = vp[2];
        float s = TR ? sample_tr(xtb, lane, vx, vy, vz)
                     : sample_cm(xb, vx, vy, vz);
        stage[p][lane] = s;
        if (lane < 8) {
            float v = 0.0f;
            if      (lane == 0) v = vx;
            else if (lane == 1) v = vy;
            else if (lane == 2) v = vz;
            else if (lane == 3) v = sv0;
            else if (lane == 4) v = sv1;
            else if (lane == 5) v = sv2;
            else if (lane == 6) v = sv3;
            stage[p][64 + lane] = v;   // lane 7 -> slot 71 = 0 pad
            if (lane < 3) cst[p][lane] = v;
        }
    }
    __syncthreads();

    // ---- merged pass: point head + nh1(column 0) + delta head share stage reads ----
    float pf[Pc], h0[Pc], dl[Pc];
    {
        float pb = ph_b[lane];
        float hb = nh1_b[lane];
        float db = (lane < 24) ? delta_b[lane] : 0.0f;
#pragma unroll
        for (int p = 0; p < Pc; ++p) { pf[p] = pb; h0[p] = hb; dl[p] = db; }
    }
    {
        const float* wp = ws + PH_OFF  + lane * 4;
        const float* w1 = ws + NH1_OFF + lane * 4;
        const float* wd = ws + DL_OFF  + lane * 4;   // lanes>=24 read in-ws junk, unused
#pragma unroll 2
        for (int jg = 0; jg < 17; ++jg) {
            float4 a = *(const float4*)(wp + jg * 256);
            float4 c = *(const float4*)(w1 + jg * 256);
            float4 d = *(const float4*)(wd + jg * 96);
#pragma unroll
            for (int p = 0; p < Pc; ++p) {
                float4 s = *(const float4*)&stage[p][jg * 4];
                pf[p] = fmaf(a.x, s.x, fmaf(a.y, s.y, fmaf(a.z, s.z, fmaf(a.w, s.w, pf[p]))));
                h0[p] = fmaf(c.x, s.x, fmaf(c.y, s.y, fmaf(c.z, s.z, fmaf(c.w, s.w, h0[p]))));
                dl[p] = fmaf(d.x, s.x, fmaf(d.y, s.y, fmaf(d.z, s.z, fmaf(d.w, s.w, dl[p]))));
            }
        }
        {   // delta group 17 (inputs 68..71)
            float4 d = *(const float4*)(wd + 17 * 96);
#pragma unroll
            for (int p = 0; p < Pc; ++p) {
                float4 s = *(const float4*)&stage[p][68];
                dl[p] = fmaf(d.x, s.x, fmaf(d.y, s.y, fmaf(d.z, s.z, fmaf(d.w, s.w, dl[p]))));
            }
        }
    }
#pragma unroll
    for (int p = 0; p < Pc; ++p) hstage[p][lane] = gelu_exact(h0[p]);
    if (lane < 24) {
#pragma unroll
        for (int p = 0; p < Pc; ++p) dls[p][lane] = dl[p];
    }
    __syncthreads();

    // ---- nh2, column 0 ----
    float nf[Pc];
#pragma unroll
    for (int p = 0; p < Pc; ++p) nf[p] = 0.0f;
    const float* __restrict__ n1w = ws + NH1_OFF + lane * 4;
    const float* __restrict__ n2w = ws + NH2_OFF + lane * 4;
    const float b1 = nh1_b[lane];
#pragma unroll 2
    for (int cg = 0; cg < 16; ++cg) {
        float4 w = *(const float4*)(n2w + cg * 256);
#pragma unroll
        for (int p = 0; p < Pc; ++p) {
            float4 s = *(const float4*)&hstage[p][cg * 4];
            nf[p] = fmaf(w.x, s.x, fmaf(w.y, s.y, fmaf(w.z, s.z, fmaf(w.w, s.w, nf[p]))));
        }
    }

    // ---- columns 1..8 = learned neighbours ----
#pragma unroll 1
    for (int k = 0; k < Kc; ++k) {
#pragma unroll
        for (int p = 0; p < Pc; ++p) {
            float nx = cst[p][0] + dls[p][3 * k + 0];
            float ny = cst[p][1] + dls[p][3 * k + 1];
            float nz = cst[p][2] + dls[p][3 * k + 2];
            float s = TR ? sample_tr(xtb, lane, nx, ny, nz)
                         : sample_cm(xb, nx, ny, nz);
            stage[p][lane] = s;
            if (lane < 4) {
                float v = (lane == 0) ? nx : (lane == 1) ? ny
                        : (lane == 2) ? nz : 0.0f;   // slot 67 = 0 pad (weight is 0 anyway)
                stage[p][64 + lane] = v;
            }
        }
        __syncthreads();

        float h[Pc];
#pragma unroll
        for (int p = 0; p < Pc; ++p) h[p] = b1;
#pragma unroll 2
        for (int jg = 0; jg < 17; ++jg) {
            float4 w = *(const float4*)(n1w + jg * 256);
#pragma unroll
            for (int p = 0; p < Pc; ++p) {
                float4 s = *(const float4*)&stage[p][jg * 4];
                h[p] = fmaf(w.x, s.x, fmaf(w.y, s.y, fmaf(w.z, s.z, fmaf(w.w, s.w, h[p]))));
            }
        }
#pragma unroll
        for (int p = 0; p < Pc; ++p) hstage[p][lane] = gelu_exact(h[p]);
        __syncthreads();

        const float* __restrict__ w2 = n2w + (size_t)(k + 1) * 4096;
#pragma unroll 2
        for (int cg = 0; cg < 16; ++cg) {
            float4 w = *(const float4*)(w2 + cg * 256);
#pragma unroll
            for (int p = 0; p < Pc; ++p) {
                float4 s = *(const float4*)&hstage[p][cg * 4];
                nf[p] = fmaf(w.x, s.x, fmaf(w.y, s.y, fmaf(w.z, s.z, fmaf(w.w, s.w, nf[p]))));
            }
        }
    }

    // ---- store out[b, n, c] = pfeat + nfeat ----
#pragma unroll
    for (int p = 0; p < Pc; ++p) {
        out[(size_t)(g0 + p) * Cc + lane] = pf[p] + nf[p];
    }
}

// ---------------- launch ----------------
extern "C" void kernel_launch(void* const* d_in, const int* in_sizes, int n_in,
                              void* d_out, int out_size, void* d_ws, size_t ws_size,
                              hipStream_t stream) {
    const float* x       = (const float*)d_in[0];
    const float* verts   = (const float*)d_in[1];
    const float* shape_w = (const float*)d_in[2];
    const float* shape_b = (const float*)d_in[3];
    const float* delta_w = (const float*)d_in[4];
    const float* delta_b = (const float*)d_in[5];
    const float* ph_w    = (const float*)d_in[6];
    const float* ph_b    = (const float*)d_in[7];
    const float* nh1_w   = (const float*)d_in[8];
    const float* nh1_b   = (const float*)d_in[9];
    const float* nh2_w   = (const float*)d_in[10];
    float* out = (float*)d_out;
    float* ws  = (float*)d_ws;
    ushort* xt = (ushort*)(ws + XT_OFF);

    sb_pack<<<144, 256, 0, stream>>>(shape_w, shape_b, delta_w, ph_w, nh1_w, nh2_w, ws);

    const size_t need = (size_t)XT_OFF * 4 + XT_USHORTS * 2;
    if (ws_size >= need) {
        sb_transpose<<<Bc * 4096, 256, 0, stream>>>(x, xt);
        sb_main<true><<<NBATCH, 64, 0, stream>>>(x, xt, verts, ws, ph_b, delta_b, nh1_b, out);
    } else {
        sb_main<false><<<NBATCH, 64, 0, stream>>>(x, xt, verts, ws, ph_b, delta_b, nh1_b, out);
    }
}

// Round 8
// 417.291 us; speedup vs baseline: 1.3952x; 1.3952x over previous
//
#include <hip/hip_runtime.h>
#include <math.h>

// ---------------- problem constants ----------------
constexpr int Bc = 2, Cc = 64, Nc = 50000, Kc = 8;
constexpr int PT = 16;                       // points per wave (MFMA M dim)
constexpr int NBLK = (Bc * Nc) / PT;         // 6250

// ---------------- ws byte layout ----------------
constexpr int BIAS_PH = 16;                  // f32[64]
constexpr int BIAS_N1 = 272;                 // f32[64]
constexpr int BIAS_DL = 528;                 // f32[32] (sv folded, padded)
constexpr int B_PH  = 1024;                  // 12 frags * 1KB
constexpr int B_N1  = 13312;                 // 12 frags
constexpr int B_DH  = 25600;                 // 6 frags (delta hi)
constexpr int B_DLO = 31744;                 // 6 frags (delta lo)
constexpr int B_N2  = 37888;                 // 72 frags -> ends 111616
constexpr size_t XT_BYTE = 262144;           // bf16 volume starts here
constexpr size_t XT_USHORTS = (size_t)Bc * 64 * 64 * 64 * 64;

using bf16x8 = __attribute__((ext_vector_type(8))) short;
using f32x4  = __attribute__((ext_vector_type(4))) float;

// ---------------- helpers ----------------
__device__ __forceinline__ float gelu_exact(float v) {
    return 0.5f * v * (1.0f + erff(v * 0.70710678118654752f));
}
__device__ __forceinline__ ushort f2bf(float f) {           // RNE f32 -> bf16 bits
    unsigned u = __float_as_uint(f);
    unsigned r = (u + 0x7FFFu + ((u >> 16) & 1u)) >> 16;
    return (ushort)r;
}
__device__ __forceinline__ float bf2f(ushort u) {
    return __uint_as_float(((unsigned)u) << 16);
}

// ---- transposed channel-minor bf16 sampling: 1 cache line per corner ----
__device__ __forceinline__ float sample_tr(const ushort* __restrict__ xtb, int lane,
                                           float gx, float gy, float gz) {
    float ix = fminf(fmaxf((gx + 1.0f) * 31.5f, 0.0f), 63.0f);
    float iy = fminf(fmaxf((gy + 1.0f) * 31.5f, 0.0f), 63.0f);
    float iz = fminf(fmaxf((gz + 1.0f) * 31.5f, 0.0f), 63.0f);
    float fx0 = floorf(ix), fy0 = floorf(iy), fz0 = floorf(iz);
    int x0 = (int)fx0, y0 = (int)fy0, z0 = (int)fz0;
    float fx = ix - fx0, fy = iy - fy0, fz = iz - fz0;
    int dx = (x0 < 63) ? 64 : 0;
    int dy = (y0 < 63) ? 4096 : 0;
    int dz = (z0 < 63) ? 262144 : 0;
    const ushort* r = xtb + ((((z0 << 12) + (y0 << 6) + x0) << 6) + lane);
    float v000 = bf2f(r[0]),       v001 = bf2f(r[dx]);
    float v010 = bf2f(r[dy]),      v011 = bf2f(r[dy + dx]);
    float v100 = bf2f(r[dz]),      v101 = bf2f(r[dz + dx]);
    float v110 = bf2f(r[dz + dy]), v111 = bf2f(r[dz + dy + dx]);
    float c00 = fmaf(fx, v001 - v000, v000);
    float c01 = fmaf(fx, v011 - v010, v010);
    float c10 = fmaf(fx, v101 - v100, v100);
    float c11 = fmaf(fx, v111 - v110, v110);
    float c0  = fmaf(fy, c01 - c00, c00);
    float c1  = fmaf(fy, c11 - c10, c10);
    return fmaf(fz, c1 - c0, c0);
}

// ---- fallback (channel-major f32) sampling ----
__device__ __forceinline__ float sample_cm(const float* __restrict__ xb,
                                           float gx, float gy, float gz) {
    float ix = fminf(fmaxf((gx + 1.0f) * 31.5f, 0.0f), 63.0f);
    float iy = fminf(fmaxf((gy + 1.0f) * 31.5f, 0.0f), 63.0f);
    float iz = fminf(fmaxf((gz + 1.0f) * 31.5f, 0.0f), 63.0f);
    float fx0 = floorf(ix), fy0 = floorf(iy), fz0 = floorf(iz);
    int x0 = (int)fx0, y0 = (int)fy0, z0 = (int)fz0;
    float fx = ix - fx0, fy = iy - fy0, fz = iz - fz0;
    int x1 = (x0 < 63) ? x0 + 1 : 63;
    int dy = (y0 < 63) ? 64 : 0;
    int dz = (z0 < 63) ? 4096 : 0;
    const float* r = xb + ((z0 << 12) + (y0 << 6));
    float v000 = r[x0],           v001 = r[x1];
    float v010 = r[x0 + dy],      v011 = r[x1 + dy];
    float v100 = r[x0 + dz],      v101 = r[x1 + dz];
    float v110 = r[x0 + dy + dz], v111 = r[x1 + dy + dz];
    float c00 = fmaf(fx, v001 - v000, v000);
    float c01 = fmaf(fx, v011 - v010, v010);
    float c10 = fmaf(fx, v101 - v100, v100);
    float c11 = fmaf(fx, v111 - v110, v110);
    float c0  = fmaf(fy, c01 - c00, c00);
    float c1  = fmaf(fy, c11 - c10, c10);
    return fmaf(fz, c1 - c0, c0);
}

// ---------------- weight packing: B-fragment lane order, bf16 ----------------
__global__ void sb_pack(const float* __restrict__ shape_w, const float* __restrict__ shape_b,
                        const float* __restrict__ delta_w, const float* __restrict__ delta_b,
                        const float* __restrict__ ph_w, const float* __restrict__ ph_b,
                        const float* __restrict__ nh1_w, const float* __restrict__ nh1_b,
                        const float* __restrict__ nh2_w, char* __restrict__ wsb) {
    int tid = blockIdx.x * blockDim.x + threadIdx.x;
    int nt  = gridDim.x * blockDim.x;
    float*  bph = (float*)(wsb + BIAS_PH);
    float*  bn1 = (float*)(wsb + BIAS_N1);
    float*  bdl = (float*)(wsb + BIAS_DL);
    ushort* wph = (ushort*)(wsb + B_PH);
    ushort* wn1 = (ushort*)(wsb + B_N1);
    ushort* wdh = (ushort*)(wsb + B_DH);
    ushort* wdl = (ushort*)(wsb + B_DLO);
    ushort* wn2 = (ushort*)(wsb + B_N2);

    for (int e = tid; e < 64; e += nt) { bph[e] = ph_b[e]; bn1[e] = nh1_b[e]; }
    for (int e = tid; e < 32; e += nt) {
        float v = 0.0f;
        if (e < 24) {
            v = delta_b[e];
#pragma unroll
            for (int i = 0; i < 4; ++i) {   // fold shape_vec (constant) into bias, f32 exact
                float sv = 64.0f * (shape_w[i*4] + shape_w[i*4+1] + shape_w[i*4+2] + shape_w[i*4+3])
                         + shape_b[i];
                v += sv * delta_w[e * 71 + 67 + i];
            }
        }
        bdl[e] = v;
    }
    // ph / nh1: 12 frags each; frag = kt*4+n; B[k][col], lane l: k=(kt*32+(l>>4)*8+j), col=n*16+(l&15)
    for (int e = tid; e < 6144; e += nt) {
        int frag = e >> 9, lane = (e >> 3) & 63, j = e & 7;
        int kt = frag >> 2, n = frag & 3;
        int k = kt * 32 + ((lane >> 4) << 3) + j;
        int col = n * 16 + (lane & 15);
        wph[e] = (k < 67) ? f2bf(ph_w[col * 67 + k])  : (ushort)0;
        wn1[e] = (k < 67) ? f2bf(nh1_w[col * 67 + k]) : (ushort)0;
    }
    // delta hi/lo: 6 frags; frag = kt*2+n (n-tiles cols 0..31, real 0..23); K cols 67..70 folded -> 0
    for (int e = tid; e < 3072; e += nt) {
        int frag = e >> 9, lane = (e >> 3) & 63, j = e & 7;
        int kt = frag >> 1, n = frag & 1;
        int k = kt * 32 + ((lane >> 4) << 3) + j;
        int col = n * 16 + (lane & 15);
        float w = (col < 24 && k < 67) ? delta_w[col * 71 + k] : 0.0f;
        ushort hi = f2bf(w);
        wdh[e] = hi;
        wdl[e] = f2bf(w - bf2f(hi));
    }
    // nh2: 72 frags; frag = c9*8 + kt*4 + n ; B[k=c'][col=c] = nh2_w[c][c'][c9]
    for (int e = tid; e < 36864; e += nt) {
        int frag = e >> 9, lane = (e >> 3) & 63, j = e & 7;
        int c9 = frag >> 3, kt = (frag >> 2) & 1, n = frag & 3;
        int k = kt * 32 + ((lane >> 4) << 3) + j;
        int c = n * 16 + (lane & 15);
        wn2[e] = f2bf(nh2_w[(c * 64 + k) * 9 + c9]);
    }
}

// ---------------- transpose x [B,C,64^3] f32 -> xt [B,64^3,C] bf16 ----------------
__global__ __launch_bounds__(256) void sb_transpose(const float* __restrict__ x,
                                                    ushort* __restrict__ xt) {
    __shared__ float tile[64][65];
    int blk = blockIdx.x;
    int b = blk >> 12, zy = blk & 4095;
    const float* __restrict__ src = x + ((size_t)b << 24) + zy * 64;
    unsigned* __restrict__ dst32 = (unsigned*)(xt + ((size_t)b << 24) + (size_t)zy * 4096);
    int t = threadIdx.x;
    int xx = t & 63, c0 = t >> 6;
#pragma unroll
    for (int i = 0; i < 16; ++i) {
        int c = i * 4 + c0;
        tile[c][xx] = src[((size_t)c << 18) + xx];
    }
    __syncthreads();
    int cp = t & 31, xs0 = t >> 5;
#pragma unroll
    for (int i = 0; i < 8; ++i) {
        int xs = i * 8 + xs0;
        unsigned lo = f2bf(tile[cp * 2][xs]);
        unsigned hi = f2bf(tile[cp * 2 + 1][xs]);
        dst32[xs * 32 + cp] = lo | (hi << 16);
    }
}

// ---------------- main MFMA kernel: 1 wave = 16 points ----------------
__global__ __launch_bounds__(64) void sb_main_mfma(
        const ushort* __restrict__ xt, const float* __restrict__ verts,
        const char* __restrict__ wsb, float* __restrict__ out) {
    __shared__ __align__(16) ushort stage[PT * 104];  // A matrix: [point][K..95], pad stride 104
    __shared__ __align__(16) ushort hst[PT * 72];     // gelu(h) A matrix: [point][64], stride 72
    __shared__ float cst[PT * 4];                     // vertex coords
    __shared__ float nbc[PT * 4];                     // current column coords (f32)
    __shared__ float dls[PT * 32];                    // delta outputs

    const int lane = threadIdx.x;
    const int l15 = lane & 15, lg = lane >> 4;
    const int g0 = blockIdx.x * PT;
    const ushort* __restrict__ xtb = xt + ((size_t)(g0 / Nc) << 24);

    const float*  bph = (const float*)(wsb + BIAS_PH);
    const float*  bn1 = (const float*)(wsb + BIAS_N1);
    const float*  bdl = (const float*)(wsb + BIAS_DL);
    const ushort* Wph = (const ushort*)(wsb + B_PH);
    const ushort* Wn1 = (const ushort*)(wsb + B_N1);
    const ushort* Wdh = (const ushort*)(wsb + B_DH);
    const ushort* Wdl = (const ushort*)(wsb + B_DLO);
    const ushort* Wn2 = (const ushort*)(wsb + B_N2);

    // ---- CRITICAL: zero-init the A tile. Pad cols 72..103 are read by MFMA
    // (k up to 95) against zero weights; uninitialized LDS there can hold
    // Inf/NaN bit patterns and NaN*0 = NaN inside the matrix dot product.
#pragma unroll
    for (int i = 0; i < (PT * 104) / 64; ++i) stage[i * 64 + lane] = 0;

    float bias_p[4], bias_h[4], bias_d[2];
#pragma unroll
    for (int n = 0; n < 4; ++n) { bias_p[n] = bph[n*16 + l15]; bias_h[n] = bn1[n*16 + l15]; }
#pragma unroll
    for (int n = 0; n < 2; ++n) bias_d[n] = bdl[n*16 + l15];

    // init: verts -> cst/nbc + stage coord block (cols 64..71; 67.. zero, weights zero-padded)
    if (lane < PT) {
        const float* vp = verts + (size_t)(g0 + lane) * 3;
        float x = vp[0], y = vp[1], z = vp[2];
        cst[lane*4+0] = x; cst[lane*4+1] = y; cst[lane*4+2] = z;
        nbc[lane*4+0] = x; nbc[lane*4+1] = y; nbc[lane*4+2] = z;
        uint4 cw;
        cw.x = (unsigned)f2bf(x) | ((unsigned)f2bf(y) << 16);
        cw.y = (unsigned)f2bf(z);
        cw.z = 0u; cw.w = 0u;
        *(uint4*)(stage + lane * 104 + 64) = cw;
    }
    __syncthreads();

    // ---- sample column 0 (lane = channel; 1 cache line per wave per corner) ----
#pragma unroll 4
    for (int p = 0; p < PT; ++p) {
        float s = sample_tr(xtb, lane, nbc[p*4], nbc[p*4+1], nbc[p*4+2]);
        stage[p * 104 + lane] = f2bf(s);
    }
    __syncthreads();

    // ---- merged GEMM pass: ph + nh1(col0) + delta(hi+lo), K=96 (3 ksteps) ----
    f32x4 pf[4], nf[4], hh[4], dd[2];
#pragma unroll
    for (int n = 0; n < 4; ++n) {
        pf[n] = (f32x4){bias_p[n], bias_p[n], bias_p[n], bias_p[n]};
        hh[n] = (f32x4){bias_h[n], bias_h[n], bias_h[n], bias_h[n]};
        nf[n] = (f32x4){0.f, 0.f, 0.f, 0.f};
    }
#pragma unroll
    for (int n = 0; n < 2; ++n) dd[n] = (f32x4){bias_d[n], bias_d[n], bias_d[n], bias_d[n]};

#pragma unroll
    for (int kt = 0; kt < 3; ++kt) {
        bf16x8 a = *(const bf16x8*)(stage + l15 * 104 + kt * 32 + lg * 8);
#pragma unroll
        for (int n = 0; n < 4; ++n) {
            bf16x8 bw = *(const bf16x8*)(Wph + ((kt*4 + n) << 9) + lane * 8);
            pf[n] = __builtin_amdgcn_mfma_f32_16x16x32_bf16(a, bw, pf[n], 0, 0, 0);
            bf16x8 b1 = *(const bf16x8*)(Wn1 + ((kt*4 + n) << 9) + lane * 8);
            hh[n] = __builtin_amdgcn_mfma_f32_16x16x32_bf16(a, b1, hh[n], 0, 0, 0);
        }
#pragma unroll
        for (int n = 0; n < 2; ++n) {
            bf16x8 bh = *(const bf16x8*)(Wdh + ((kt*2 + n) << 9) + lane * 8);
            dd[n] = __builtin_amdgcn_mfma_f32_16x16x32_bf16(a, bh, dd[n], 0, 0, 0);
            bf16x8 bl = *(const bf16x8*)(Wdl + ((kt*2 + n) << 9) + lane * 8);
            dd[n] = __builtin_amdgcn_mfma_f32_16x16x32_bf16(a, bl, dd[n], 0, 0, 0);
        }
    }
    // D layout: row=(lg*4+r) [point], col=n*16+l15
#pragma unroll
    for (int n = 0; n < 2; ++n)
#pragma unroll
        for (int r = 0; r < 4; ++r)
            dls[(lg*4 + r) * 32 + n*16 + l15] = dd[n][r];
#pragma unroll
    for (int n = 0; n < 4; ++n)
#pragma unroll
        for (int r = 0; r < 4; ++r)
            hst[(lg*4 + r) * 72 + n*16 + l15] = f2bf(gelu_exact(hh[n][r]));
    __syncthreads();

    // ---- nh2 column 0 (K=64, 2 ksteps) ----
#pragma unroll
    for (int kt = 0; kt < 2; ++kt) {
        bf16x8 a = *(const bf16x8*)(hst + l15 * 72 + kt * 32 + lg * 8);
#pragma unroll
        for (int n = 0; n < 4; ++n) {
            bf16x8 bw = *(const bf16x8*)(Wn2 + ((kt*4 + n) << 9) + lane * 8);
            nf[n] = __builtin_amdgcn_mfma_f32_16x16x32_bf16(a, bw, nf[n], 0, 0, 0);
        }
    }

    // ---- neighbour columns 1..8 ----
    for (int k = 0; k < Kc; ++k) {
        if (lane < PT) {
            float x = cst[lane*4+0] + dls[lane*32 + 3*k + 0];
            float y = cst[lane*4+1] + dls[lane*32 + 3*k + 1];
            float z = cst[lane*4+2] + dls[lane*32 + 3*k + 2];
            nbc[lane*4+0] = x; nbc[lane*4+1] = y; nbc[lane*4+2] = z;
            uint4 cw;
            cw.x = (unsigned)f2bf(x) | ((unsigned)f2bf(y) << 16);
            cw.y = (unsigned)f2bf(z);
            cw.z = 0u; cw.w = 0u;
            *(uint4*)(stage + lane * 104 + 64) = cw;
        }
        __syncthreads();
#pragma unroll 4
        for (int p = 0; p < PT; ++p) {
            float s = sample_tr(xtb, lane, nbc[p*4], nbc[p*4+1], nbc[p*4+2]);
            stage[p * 104 + lane] = f2bf(s);
        }
        __syncthreads();

        f32x4 hk[4];
#pragma unroll
        for (int n = 0; n < 4; ++n) hk[n] = (f32x4){bias_h[n], bias_h[n], bias_h[n], bias_h[n]};
#pragma unroll
        for (int kt = 0; kt < 3; ++kt) {
            bf16x8 a = *(const bf16x8*)(stage + l15 * 104 + kt * 32 + lg * 8);
#pragma unroll
            for (int n = 0; n < 4; ++n) {
                bf16x8 b1 = *(const bf16x8*)(Wn1 + ((kt*4 + n) << 9) + lane * 8);
                hk[n] = __builtin_amdgcn_mfma_f32_16x16x32_bf16(a, b1, hk[n], 0, 0, 0);
            }
        }
#pragma unroll
        for (int n = 0; n < 4; ++n)
#pragma unroll
            for (int r = 0; r < 4; ++r)
                hst[(lg*4 + r) * 72 + n*16 + l15] = f2bf(gelu_exact(hk[n][r]));
        __syncthreads();

        const ushort* Wk = Wn2 + ((size_t)(k + 1) << 12);   // (k+1)*8 frags * 512
#pragma unroll
        for (int kt = 0; kt < 2; ++kt) {
            bf16x8 a = *(const bf16x8*)(hst + l15 * 72 + kt * 32 + lg * 8);
#pragma unroll
            for (int n = 0; n < 4; ++n) {
                bf16x8 bw = *(const bf16x8*)(Wk + ((kt*4 + n) << 9) + lane * 8);
                nf[n] = __builtin_amdgcn_mfma_f32_16x16x32_bf16(a, bw, nf[n], 0, 0, 0);
            }
        }
    }

    // ---- store out[point][channel] = pf + nf ----
#pragma unroll
    for (int n = 0; n < 4; ++n)
#pragma unroll
        for (int r = 0; r < 4; ++r)
            out[(size_t)(g0 + lg*4 + r) * 64 + n*16 + l15] = pf[n][r] + nf[n][r];
}

// ---------------- correctness fallback (only if ws too small; slow, f32) ----------------
__global__ __launch_bounds__(64) void sb_fallback(
        const float* __restrict__ x, const float* __restrict__ verts,
        const float* __restrict__ shape_w, const float* __restrict__ shape_b,
        const float* __restrict__ delta_w, const float* __restrict__ delta_b,
        const float* __restrict__ ph_w, const float* __restrict__ ph_b,
        const float* __restrict__ nh1_w, const float* __restrict__ nh1_b,
        const float* __restrict__ nh2_w, float* __restrict__ out) {
    __shared__ float cp[72];
    __shared__ float hcol[64];
    __shared__ float dl[24];
    int lane = threadIdx.x;
    int g = blockIdx.x;
    int b = g / Nc;
    const float* xb = x + ((size_t)(b * 64 + lane) << 18);
    float vx = verts[g*3], vy = verts[g*3+1], vz = verts[g*3+2];
    cp[lane] = sample_cm(xb, vx, vy, vz);
    if (lane < 8) {
        float v = 0.0f;
        if      (lane == 0) v = vx;
        else if (lane == 1) v = vy;
        else if (lane == 2) v = vz;
        else if (lane < 7) {
            int i = lane - 3;
            v = 64.0f*(shape_w[i*4]+shape_w[i*4+1]+shape_w[i*4+2]+shape_w[i*4+3]) + shape_b[i];
        }
        cp[64 + lane] = v;
    }
    __syncthreads();
    float pfv = ph_b[lane];
    for (int j = 0; j < 67; ++j) pfv += ph_w[lane*67 + j] * cp[j];
    if (lane < 24) {
        float s = delta_b[lane];
        for (int j = 0; j < 71; ++j) s += delta_w[lane*71 + j] * cp[j];
        dl[lane] = s;
    }
    float h = nh1_b[lane];
    for (int j = 0; j < 67; ++j) h += nh1_w[lane*67 + j] * cp[j];
    hcol[lane] = gelu_exact(h);
    __syncthreads();
    float nfv = 0.0f;
    for (int c2 = 0; c2 < 64; ++c2) nfv += nh2_w[(lane*64 + c2)*9] * hcol[c2];
    for (int k = 0; k < 8; ++k) {
        __syncthreads();
        float nx = vx + dl[3*k], ny = vy + dl[3*k+1], nz = vz + dl[3*k+2];
        cp[lane] = sample_cm(xb, nx, ny, nz);
        if (lane < 3) cp[64 + lane] = (lane == 0) ? nx : (lane == 1) ? ny : nz;
        __syncthreads();
        float hv = nh1_b[lane];
        for (int j = 0; j < 67; ++j) hv += nh1_w[lane*67 + j] * cp[j];
        hcol[lane] = gelu_exact(hv);
        __syncthreads();
        for (int c2 = 0; c2 < 64; ++c2) nfv += nh2_w[(lane*64 + c2)*9 + k + 1] * hcol[c2];
    }
    out[(size_t)g * 64 + lane] = pfv + nfv;
}

// ---------------- launch ----------------
extern "C" void kernel_launch(void* const* d_in, const int* in_sizes, int n_in,
                              void* d_out, int out_size, void* d_ws, size_t ws_size,
                              hipStream_t stream) {
    const float* x       = (const float*)d_in[0];
    const float* verts   = (const float*)d_in[1];
    const float* shape_w = (const float*)d_in[2];
    const float* shape_b = (const float*)d_in[3];
    const float* delta_w = (const float*)d_in[4];
    const float* delta_b = (const float*)d_in[5];
    const float* ph_w    = (const float*)d_in[6];
    const float* ph_b    = (const float*)d_in[7];
    const float* nh1_w   = (const float*)d_in[8];
    const float* nh1_b   = (const float*)d_in[9];
    const float* nh2_w   = (const float*)d_in[10];
    float* out = (float*)d_out;
    char*  wsb = (char*)d_ws;

    const size_t need = XT_BYTE + XT_USHORTS * 2;   // identical to rounds 3-6 (passed)
    if (ws_size >= need) {
        ushort* xt = (ushort*)(wsb + XT_BYTE);
        sb_pack<<<96, 256, 0, stream>>>(shape_w, shape_b, delta_w, delta_b,
                                        ph_w, ph_b, nh1_w, nh1_b, nh2_w, wsb);
        sb_transpose<<<Bc * 4096, 256, 0, stream>>>(x, xt);
        sb_main_mfma<<<NBLK, 64, 0, stream>>>(xt, verts, wsb, out);
    } else {
        sb_fallback<<<Bc * Nc, 64, 0, stream>>>(x, verts, shape_w, shape_b, delta_w, delta_b,
                                                ph_w, ph_b, nh1_w, nh1_b, nh2_w, out);
    }
}